// Round 10
// baseline (132.595 us; speedup 1.0000x reference)
//
#include <hip/hip_runtime.h>
#include <hip/hip_bf16.h>

// ---------------------------------------------------------------------------
// AttentionLayer: per-token MLP(256->80->40->1) + masked softmax.
// din@W1 = t@U + [s | t*s] @ [V;X].  Layer-1 computed TRANSPOSED:
// acc = mfma(A=W1frag, B=dinfrag) -> lane holds H1^T[chan=16nt+4kq+j][tok=cb].
// Layer-2 B-frags assembled lane-locally from acc against sigma-permuted
// W2^T (sigma(kt,kq,e) = 32kt + 16*(e>=4) + 4kq + (e&3)). Bias in MFMA C-init.
// Round-10: DEPTH-3 rotating register prefetch (SA/SB/SC, static names),
// STAGE(t+3) issued right after pk8 frees the buffer -> ~12KB in flight/wave
// (~48KB/SIMD, 2x prior). Funded by moving bL2 (36 VGPR) to padded LDS
// (stride 208B, <=2-way conflicts) and bw/wv (24 VGPR) to LDS f32x4
// broadcasts. Numerics identical to passing R9. __launch_bounds__(256,2)
// (R5/R8: (,4) forces VGPR=64 -> catastrophic spill).
// LDS = 20480 + 9984 + 384 = 30,848 B -> 4 blocks/CU possible.
// ---------------------------------------------------------------------------

#define WS_WCT   0        // bf16 [80][128] PRE-SWIZZLED: u16 idx = c*128 + (k ^ ((c&7)<<3))
#define WS_W2T   20480    // bf16 [48][96]  sigma-permuted W2T (zero-padded)
#define WS_B2P   29696    // f32  [48]
#define WS_W3P   29888    // f32  [48]
#define WS_U     30080    // f32  [64][80]  U[d][h] = W1a+W1c   (ends at 50560)

typedef __attribute__((ext_vector_type(8))) short short8;
typedef __attribute__((ext_vector_type(4))) float f32x4;

static __device__ __forceinline__ unsigned short f2bf(float f) {
    unsigned int u = __builtin_bit_cast(unsigned int, f);
    u = (u + 0x7FFFu + ((u >> 16) & 1u)) >> 16;   // RNE, finite inputs
    return (unsigned short)u;
}

static __device__ __forceinline__ short8 pk8(float4 a, float4 b) {
    short8 r;
    r[0] = (short)f2bf(a.x); r[1] = (short)f2bf(a.y);
    r[2] = (short)f2bf(a.z); r[3] = (short)f2bf(a.w);
    r[4] = (short)f2bf(b.x); r[5] = (short)f2bf(b.y);
    r[6] = (short)f2bf(b.z); r[7] = (short)f2bf(b.w);
    return r;
}

// ---------------- weight prep (1 block) ------------------------------------
__global__ __launch_bounds__(256) void prep_w_kernel(
    const float* __restrict__ W1, const float* __restrict__ W2,
    const float* __restrict__ b2, const float* __restrict__ W3,
    unsigned char* __restrict__ ws)
{
    const int tid = threadIdx.x;
    unsigned short* wcT = (unsigned short*)(ws + WS_WCT);
    for (int idx = tid; idx < 80 * 128; idx += 256) {
        int c = idx >> 7, k = idx & 127;
        float v;
        if (k < 64) v = W1[(64 + k) * 80 + c] - W1[(128 + k) * 80 + c]; // V
        else        v = W1[(192 + (k - 64)) * 80 + c];                  // X
        wcT[(c << 7) + (k ^ ((c & 7) << 3))] = f2bf(v);                 // swizzled
    }
    // sigma-permuted W2T: storage [c2][ks], ks=(kt,kq,e) -> real chan
    unsigned short* w2T = (unsigned short*)(ws + WS_W2T);
    for (int idx = tid; idx < 48 * 96; idx += 256) {
        int c2 = idx / 96, ks = idx - c2 * 96;
        int kt = ks >> 5, kq = (ks >> 3) & 3, e = ks & 7;
        int chan = 32 * kt + 16 * (e >> 2) + 4 * kq + (e & 3);
        float v = (c2 < 40 && chan < 80) ? W2[chan * 40 + c2] : 0.0f;
        w2T[idx] = f2bf(v);
    }
    float* b2p = (float*)(ws + WS_B2P);
    float* w3p = (float*)(ws + WS_W3P);
    for (int idx = tid; idx < 48; idx += 256) {
        b2p[idx] = (idx < 40) ? b2[idx] : 0.0f;
        w3p[idx] = (idx < 40) ? W3[idx] : 0.0f;
    }
    float* Uf = (float*)(ws + WS_U);
    for (int idx = tid; idx < 64 * 80; idx += 256) {
        int d = idx / 80, h = idx - d * 80;
        Uf[idx] = W1[d * 80 + h] + W1[(128 + d) * 80 + h];
    }
}

// ---------------- streaming score kernel ------------------------------------
__global__ __launch_bounds__(256, 2) void score_kernel(
    const float* __restrict__ seq, const float* __restrict__ tgt,
    const float* __restrict__ b1g, const unsigned char* __restrict__ ws,
    float* __restrict__ out)
{
    __shared__ __align__(16) unsigned char w1s[20480];       // pre-swizzled W1
    __shared__ __align__(16) unsigned short w2s[48 * 104];   // padded stride 208B
    __shared__ __align__(16) float bwS[48];
    __shared__ __align__(16) float wvS[48];

    const int tid = threadIdx.x;
    {   // stage W1 (linear), W2 (repack to stride-104 u16 rows), bw/wv
        const float4* s1 = (const float4*)(ws + WS_WCT);
        float4* d1 = (float4*)w1s;
        #pragma unroll
        for (int i = 0; i < 5; ++i) d1[tid + 256 * i] = s1[tid + 256 * i];
        const unsigned int* s2 = (const unsigned int*)(ws + WS_W2T);
        unsigned int* d2 = (unsigned int*)w2s;
        for (int idx = tid; idx < 2304; idx += 256) {        // 48 rows x 48 u32
            int c2 = idx / 48, kk = idx - 48 * c2;
            d2[c2 * 52 + kk] = s2[idx];
        }
        if (tid < 48) {
            bwS[tid] = ((const float*)(ws + WS_B2P))[tid];
            wvS[tid] = ((const float*)(ws + WS_W3P))[tid];
        }
    }

    const int l  = tid & 63;
    const int w  = tid >> 6;
    const int cb = l & 15;
    const int kq = l >> 4;
    const int swi = (cb & 7) << 4;
    const int b  = blockIdx.x * 4 + w;            // one batch per wave

    // target fragments (constant per batch)
    const float* tp = tgt + (size_t)b * 64 + kq * 8;
    const float4 T0 = *(const float4*)tp;        const float4 T1 = *(const float4*)(tp + 4);
    const float4 T2 = *(const float4*)(tp + 32); const float4 T3 = *(const float4*)(tp + 36);

    // biasOld[nt] = b1[16nt+cb] + t@U[:,16nt+cb]  (f32, from L2)
    float biasOld[5];
    #pragma unroll
    for (int nt = 0; nt < 5; ++nt) biasOld[nt] = b1g[nt * 16 + cb];
    {
        const float* Uf = (const float*)(ws + WS_U);
        const float* tb = tgt + (size_t)b * 64;
        #pragma unroll 4
        for (int d = 0; d < 64; ++d) {
            float tA = tb[d];
            #pragma unroll
            for (int nt = 0; nt < 5; ++nt)
                biasOld[nt] += tA * Uf[d * 80 + nt * 16 + cb];
        }
    }
    // redistribute to C-row indexing: biasN[nt][j] = bias[chan=16nt+4kq+j]
    float biasN[5][4];
    #pragma unroll
    for (int nt = 0; nt < 5; ++nt)
        #pragma unroll
        for (int j = 0; j < 4; ++j)
            biasN[nt][j] = __shfl(biasOld[nt], ((l >> 4) << 2) + j, 64);

    __syncthreads();   // w1s/w2s/bwS/wvS ready

#define STAGE(TT, S0,S1,S2,S3) do {                                            \
        int row = (TT) * 16 + cb; row = row > 199 ? 199 : row;                 \
        const float* sp = seq + ((size_t)b * 200 + row) * 64 + kq * 8;         \
        S0 = *(const float4*)sp;        S1 = *(const float4*)(sp + 4);         \
        S2 = *(const float4*)(sp + 32); S3 = *(const float4*)(sp + 36);        \
    } while (0)

    // STEP: consume buffer (pk8 frees it) -> immediately STAGE tile T+3 into
    // the same registers (loads fly during the MFMA tail) -> compute tail.
#define STEP(T, DOSTAGE, S0,S1,S2,S3) do {                                     \
        short8 a0 = pk8(S0, S1), a1 = pk8(S2, S3);                             \
        short8 a2 = pk8(T0 * S0, T1 * S1), a3 = pk8(T2 * S2, T3 * S3);         \
        if (DOSTAGE) {                                                         \
            int tn = (T) + 3; tn = tn > 12 ? 12 : tn;                          \
            STAGE(tn, S0, S1, S2, S3);                                         \
        }                                                                      \
        f32x4 acc[5];                                                          \
        _Pragma("unroll")                                                      \
        for (int nt = 0; nt < 5; ++nt) {                                       \
            acc[nt][0] = biasN[nt][0]; acc[nt][1] = biasN[nt][1];              \
            acc[nt][2] = biasN[nt][2]; acc[nt][3] = biasN[nt][3];              \
        }                                                                      \
        _Pragma("unroll")                                                      \
        for (int kt = 0; kt < 4; ++kt) {                                       \
            short8 av = kt == 0 ? a0 : kt == 1 ? a1 : kt == 2 ? a2 : a3;       \
            _Pragma("unroll")                                                  \
            for (int nt = 0; nt < 5; ++nt) {                                   \
                short8 bf = *(const short8*)(w1s + (cb + 16 * nt) * 256 +      \
                                             ((kt * 64 + kq * 16) ^ swi));     \
                acc[nt] = __builtin_amdgcn_mfma_f32_16x16x32_bf16(bf, av, acc[nt], 0, 0, 0); \
            }                                                                  \
        }                                                                      \
        uint2 p[5];                                                            \
        _Pragma("unroll")                                                      \
        for (int nt = 0; nt < 5; ++nt) {                                       \
            float h0 = fmaxf(acc[nt][0], 0.0f), h1 = fmaxf(acc[nt][1], 0.0f);  \
            float h2 = fmaxf(acc[nt][2], 0.0f), h3 = fmaxf(acc[nt][3], 0.0f);  \
            p[nt].x = (unsigned)f2bf(h0) | ((unsigned)f2bf(h1) << 16);         \
            p[nt].y = (unsigned)f2bf(h2) | ((unsigned)f2bf(h3) << 16);         \
        }                                                                      \
        f32x4 acc2[3];                                                         \
        _Pragma("unroll")                                                      \
        for (int mt = 0; mt < 3; ++mt)                                         \
            acc2[mt] = *(const f32x4*)(bwS + mt * 16 + kq * 4);                \
        _Pragma("unroll")                                                      \
        for (int kt = 0; kt < 3; ++kt) {                                       \
            uint4 bb;                                                          \
            bb.x = p[2 * kt].x; bb.y = p[2 * kt].y;                            \
            bb.z = (kt < 2) ? p[2 * kt + 1].x : 0u;                            \
            bb.w = (kt < 2) ? p[2 * kt + 1].y : 0u;                            \
            short8 b2f = __builtin_bit_cast(short8, bb);                       \
            _Pragma("unroll")                                                  \
            for (int mt = 0; mt < 3; ++mt) {                                   \
                short8 w2f = *(const short8*)(w2s + (cb + 16 * mt) * 104 +     \
                                              kt * 32 + kq * 8);               \
                acc2[mt] = __builtin_amdgcn_mfma_f32_16x16x32_bf16(w2f, b2f, acc2[mt], 0, 0, 0); \
            }                                                                  \
        }                                                                      \
        float part = 0.0f;                                                     \
        _Pragma("unroll")                                                      \
        for (int mt = 0; mt < 3; ++mt) {                                       \
            f32x4 wvv = *(const f32x4*)(wvS + mt * 16 + kq * 4);               \
            _Pragma("unroll")                                                  \
            for (int j = 0; j < 4; ++j)                                        \
                part += fmaxf(acc2[mt][j], 0.0f) * wvv[j];                     \
        }                                                                      \
        part += __shfl_xor(part, 16, 64);                                      \
        part += __shfl_xor(part, 32, 64);                                      \
        if (l < 16) {                                                          \
            int row = (T) * 16 + cb;                                           \
            if (row < 200) out[(size_t)b * 200 + row] = part;                  \
        }                                                                      \
    } while (0)

    float4 sa0, sa1, sa2, sa3;
    float4 sb0, sb1, sb2, sb3;
    float4 sc0, sc1, sc2, sc3;
    STAGE(0, sa0, sa1, sa2, sa3);
    STAGE(1, sb0, sb1, sb2, sb3);
    STAGE(2, sc0, sc1, sc2, sc3);
    #pragma unroll 1
    for (int g = 0; g < 4; ++g) {
        STEP(3 * g,     1, sa0, sa1, sa2, sa3);
        STEP(3 * g + 1, 1, sb0, sb1, sb2, sb3);
        STEP(3 * g + 2, 1, sc0, sc1, sc2, sc3);
    }
    STEP(12, 0, sa0, sa1, sa2, sa3);
}

// ---------------- masked softmax, in place on d_out -------------------------
__global__ __launch_bounds__(256) void softmax_kernel(
    const int* __restrict__ mask, float* __restrict__ out)
{
    const int l = threadIdx.x & 63;
    const int w = threadIdx.x >> 6;
    const int b = blockIdx.x * 4 + w;             // grid 1024 -> 4096 batches
    float* po = out + (size_t)b * 200;
    const int* pm = mask + (size_t)b * 200;
    float v[4];
    #pragma unroll
    for (int j = 0; j < 4; ++j) {
        int tk = l + 64 * j;
        v[j] = (tk < 200) ? (pm[tk] ? po[tk] : -1.0e9f) : -3.0e38f;
    }
    float mx = fmaxf(fmaxf(v[0], v[1]), fmaxf(v[2], v[3]));
    #pragma unroll
    for (int st = 32; st >= 1; st >>= 1) mx = fmaxf(mx, __shfl_xor(mx, st, 64));
    float e[4], sm = 0.0f;
    #pragma unroll
    for (int j = 0; j < 4; ++j) {
        int tk = l + 64 * j;
        e[j] = (tk < 200) ? __expf(v[j] - mx) : 0.0f;
        sm += e[j];
    }
    #pragma unroll
    for (int st = 32; st >= 1; st >>= 1) sm += __shfl_xor(sm, st, 64);
    float inv = 1.0f / sm;
    #pragma unroll
    for (int j = 0; j < 4; ++j) {
        int tk = l + 64 * j;
        if (tk < 200) po[tk] = e[j] * inv;
    }
}

extern "C" void kernel_launch(void* const* d_in, const int* in_sizes, int n_in,
                              void* d_out, int out_size, void* d_ws, size_t ws_size,
                              hipStream_t stream)
{
    const float* seq = (const float*)d_in[0];
    const float* tgt = (const float*)d_in[1];
    const int*   msk = (const int*)d_in[2];
    const float* W1  = (const float*)d_in[3];
    const float* b1  = (const float*)d_in[4];
    const float* W2  = (const float*)d_in[5];
    const float* b2  = (const float*)d_in[6];
    const float* W3  = (const float*)d_in[7];
    // d_in[8] = b3: uniform shift, cancels in softmax.
    unsigned char* ws = (unsigned char*)d_ws;
    float* out = (float*)d_out;

    prep_w_kernel<<<1, 256, 0, stream>>>(W1, W2, b2, W3, ws);
    score_kernel<<<1024, 256, 0, stream>>>(seq, tgt, b1, ws, out);
    softmax_kernel<<<1024, 256, 0, stream>>>(msk, out);
}

// Round 11
// 109.806 us; speedup vs baseline: 1.2075x; 1.2075x over previous
//
#include <hip/hip_runtime.h>
#include <hip/hip_bf16.h>

// ---------------------------------------------------------------------------
// AttentionLayer: per-token MLP(256->80->40->1) + masked softmax.
// din@W1 = t@U + [s | t*s] @ [V;X].  Layer-1 computed TRANSPOSED:
// acc = mfma(A=W1frag, B=dinfrag) -> lane holds H1^T[chan=16nt+4kq+j][tok=cb].
// Layer-2 B-frags assembled lane-locally from acc against sigma-permuted
// W2^T (sigma(kt,kq,e) = 32kt + 16*(e>=4) + 4kq + (e&3)). Bias in MFMA C-init.
// Round-11: ALL weights in REGISTERS. R7/R9/R10 profiles showed per-tile
// period 3.6-5.6us vs 0.3us compute, pipes <20% busy: the 20 ds_read_b128
// W1-fragment reads per tile are LOOP-INVARIANT but unhoistable at the
// 128-VGPR cap -> compiler re-issued them serially every tile (~120cy each,
// m117). Fix: bL1[4][5] (80 VGPR) loaded once from ws/L2; LDS deleted
// entirely (no ds ops, no syncthreads); 64-thread blocks x 4096, R9's proven
// A/B double-buffered loop; __launch_bounds__(64,1) -> full register budget
// (R5/R8: never force waves-per-EU>=4; R10: don't add depth at a VGPR cap).
// Structural signature to verify: LDS_Block_Size=0, SQ_LDS_BANK_CONFLICT~0,
// WRITE_SIZE ~4MB (no spill).
// ---------------------------------------------------------------------------

#define WS_WCT   0        // bf16 [80][128] LINEAR: u16 idx = c*128 + k, = [V;X][k][c]
#define WS_W2T   20480    // bf16 [48][96]  sigma-permuted W2T (zero-padded)
#define WS_B2P   29696    // f32  [48]
#define WS_W3P   29888    // f32  [48]
#define WS_U     30080    // f32  [64][80]  U[d][h] = W1a+W1c   (ends at 50560)

typedef __attribute__((ext_vector_type(8))) short short8;
typedef __attribute__((ext_vector_type(4))) float f32x4;

static __device__ __forceinline__ unsigned short f2bf(float f) {
    unsigned int u = __builtin_bit_cast(unsigned int, f);
    u = (u + 0x7FFFu + ((u >> 16) & 1u)) >> 16;   // RNE, finite inputs
    return (unsigned short)u;
}

static __device__ __forceinline__ short8 pk8(float4 a, float4 b) {
    short8 r;
    r[0] = (short)f2bf(a.x); r[1] = (short)f2bf(a.y);
    r[2] = (short)f2bf(a.z); r[3] = (short)f2bf(a.w);
    r[4] = (short)f2bf(b.x); r[5] = (short)f2bf(b.y);
    r[6] = (short)f2bf(b.z); r[7] = (short)f2bf(b.w);
    return r;
}

// ---------------- weight prep (1 block) ------------------------------------
__global__ __launch_bounds__(256) void prep_w_kernel(
    const float* __restrict__ W1, const float* __restrict__ W2,
    const float* __restrict__ b2, const float* __restrict__ W3,
    unsigned char* __restrict__ ws)
{
    const int tid = threadIdx.x;
    unsigned short* wcT = (unsigned short*)(ws + WS_WCT);
    for (int idx = tid; idx < 80 * 128; idx += 256) {
        int c = idx >> 7, k = idx & 127;
        float v;
        if (k < 64) v = W1[(64 + k) * 80 + c] - W1[(128 + k) * 80 + c]; // V
        else        v = W1[(192 + (k - 64)) * 80 + c];                  // X
        wcT[idx] = f2bf(v);                                             // LINEAR
    }
    // sigma-permuted W2T: storage [c2][ks], ks=(kt,kq,e) -> real chan
    unsigned short* w2T = (unsigned short*)(ws + WS_W2T);
    for (int idx = tid; idx < 48 * 96; idx += 256) {
        int c2 = idx / 96, ks = idx - c2 * 96;
        int kt = ks >> 5, kq = (ks >> 3) & 3, e = ks & 7;
        int chan = 32 * kt + 16 * (e >> 2) + 4 * kq + (e & 3);
        float v = (c2 < 40 && chan < 80) ? W2[chan * 40 + c2] : 0.0f;
        w2T[idx] = f2bf(v);
    }
    float* b2p = (float*)(ws + WS_B2P);
    float* w3p = (float*)(ws + WS_W3P);
    for (int idx = tid; idx < 48; idx += 256) {
        b2p[idx] = (idx < 40) ? b2[idx] : 0.0f;
        w3p[idx] = (idx < 40) ? W3[idx] : 0.0f;
    }
    float* Uf = (float*)(ws + WS_U);
    for (int idx = tid; idx < 64 * 80; idx += 256) {
        int d = idx / 80, h = idx - d * 80;
        Uf[idx] = W1[d * 80 + h] + W1[(128 + d) * 80 + h];
    }
}

// ---------------- streaming score kernel: 1 wave = 1 batch ------------------
__global__ __launch_bounds__(64, 1) void score_kernel(
    const float* __restrict__ seq, const float* __restrict__ tgt,
    const float* __restrict__ b1g, const unsigned char* __restrict__ ws,
    float* __restrict__ out)
{
    const int l  = threadIdx.x;                   // 0..63
    const int cb = l & 15;
    const int kq = l >> 4;
    const int b  = blockIdx.x;                    // one batch per wave/block

    // ---- ALL weights -> registers (one-time, from ws/L2) ----
    const unsigned short* wcT = (const unsigned short*)(ws + WS_WCT);
    short8 bL1[4][5];                             // 80 VGPR, tile-invariant
    #pragma unroll
    for (int kt = 0; kt < 4; ++kt)
        #pragma unroll
        for (int nt = 0; nt < 5; ++nt)
            bL1[kt][nt] = *(const short8*)(wcT + (cb + 16 * nt) * 128 + kt * 32 + kq * 8);

    const unsigned short* w2T = (const unsigned short*)(ws + WS_W2T);
    short8 bL2[3][3];
    #pragma unroll
    for (int kt = 0; kt < 3; ++kt)
        #pragma unroll
        for (int mt = 0; mt < 3; ++mt)
            bL2[kt][mt] = *(const short8*)(w2T + (cb + 16 * mt) * 96 + kt * 32 + kq * 8);
    const float* b2p = (const float*)(ws + WS_B2P);
    const float* w3p = (const float*)(ws + WS_W3P);
    float bw[3][4], wv[3][4];
    #pragma unroll
    for (int mt = 0; mt < 3; ++mt)
        #pragma unroll
        for (int j = 0; j < 4; ++j) {
            int c2 = mt * 16 + kq * 4 + j;
            bw[mt][j] = b2p[c2]; wv[mt][j] = w3p[c2];
        }

    // target fragments (constant per batch)
    const float* tp = tgt + (size_t)b * 64 + kq * 8;
    const float4 T0 = *(const float4*)tp;        const float4 T1 = *(const float4*)(tp + 4);
    const float4 T2 = *(const float4*)(tp + 32); const float4 T3 = *(const float4*)(tp + 36);

    // biasOld[nt] = b1[16nt+cb] + t@U[:,16nt+cb]  (f32, from L2)
    float biasOld[5];
    #pragma unroll
    for (int nt = 0; nt < 5; ++nt) biasOld[nt] = b1g[nt * 16 + cb];
    {
        const float* Uf = (const float*)(ws + WS_U);
        const float* tb = tgt + (size_t)b * 64;
        #pragma unroll 4
        for (int d = 0; d < 64; ++d) {
            float tA = tb[d];
            #pragma unroll
            for (int nt = 0; nt < 5; ++nt)
                biasOld[nt] += tA * Uf[d * 80 + nt * 16 + cb];
        }
    }
    // redistribute to C-row indexing: biasN[nt][j] = bias[chan=16nt+4kq+j]
    float biasN[5][4];
    #pragma unroll
    for (int nt = 0; nt < 5; ++nt)
        #pragma unroll
        for (int j = 0; j < 4; ++j)
            biasN[nt][j] = __shfl(biasOld[nt], ((l >> 4) << 2) + j, 64);

#define STAGE(TT, S0,S1,S2,S3) do {                                            \
        int row = (TT) * 16 + cb; row = row > 199 ? 199 : row;                 \
        const float* sp = seq + ((size_t)b * 200 + row) * 64 + kq * 8;         \
        S0 = *(const float4*)sp;        S1 = *(const float4*)(sp + 4);         \
        S2 = *(const float4*)(sp + 32); S3 = *(const float4*)(sp + 36);        \
    } while (0)

#define PROC(TT, S0,S1,S2,S3) do {                                            \
        short8 a0 = pk8(S0, S1), a1 = pk8(S2, S3);                             \
        short8 a2 = pk8(T0 * S0, T1 * S1), a3 = pk8(T2 * S2, T3 * S3);         \
        f32x4 acc[5];                                                          \
        _Pragma("unroll")                                                      \
        for (int nt = 0; nt < 5; ++nt) {                                       \
            acc[nt][0] = biasN[nt][0]; acc[nt][1] = biasN[nt][1];              \
            acc[nt][2] = biasN[nt][2]; acc[nt][3] = biasN[nt][3];              \
        }                                                                      \
        _Pragma("unroll")                                                      \
        for (int kt = 0; kt < 4; ++kt) {                                       \
            short8 av = kt == 0 ? a0 : kt == 1 ? a1 : kt == 2 ? a2 : a3;       \
            _Pragma("unroll")                                                  \
            for (int nt = 0; nt < 5; ++nt)                                     \
                acc[nt] = __builtin_amdgcn_mfma_f32_16x16x32_bf16(bL1[kt][nt], av, acc[nt], 0, 0, 0); \
        }                                                                      \
        uint2 p[5];                                                            \
        _Pragma("unroll")                                                      \
        for (int nt = 0; nt < 5; ++nt) {                                       \
            float h0 = fmaxf(acc[nt][0], 0.0f), h1 = fmaxf(acc[nt][1], 0.0f);  \
            float h2 = fmaxf(acc[nt][2], 0.0f), h3 = fmaxf(acc[nt][3], 0.0f);  \
            p[nt].x = (unsigned)f2bf(h0) | ((unsigned)f2bf(h1) << 16);         \
            p[nt].y = (unsigned)f2bf(h2) | ((unsigned)f2bf(h3) << 16);         \
        }                                                                      \
        f32x4 acc2[3];                                                         \
        _Pragma("unroll")                                                      \
        for (int mt = 0; mt < 3; ++mt) {                                       \
            acc2[mt][0] = bw[mt][0]; acc2[mt][1] = bw[mt][1];                  \
            acc2[mt][2] = bw[mt][2]; acc2[mt][3] = bw[mt][3];                  \
        }                                                                      \
        _Pragma("unroll")                                                      \
        for (int kt = 0; kt < 3; ++kt) {                                       \
            uint4 bb;                                                          \
            bb.x = p[2 * kt].x; bb.y = p[2 * kt].y;                            \
            bb.z = (kt < 2) ? p[2 * kt + 1].x : 0u;                            \
            bb.w = (kt < 2) ? p[2 * kt + 1].y : 0u;                            \
            short8 b2f = __builtin_bit_cast(short8, bb);                       \
            _Pragma("unroll")                                                  \
            for (int mt = 0; mt < 3; ++mt)                                     \
                acc2[mt] = __builtin_amdgcn_mfma_f32_16x16x32_bf16(bL2[kt][mt], b2f, acc2[mt], 0, 0, 0); \
        }                                                                      \
        float part = 0.0f;                                                     \
        _Pragma("unroll")                                                      \
        for (int mt = 0; mt < 3; ++mt)                                         \
            _Pragma("unroll")                                                  \
            for (int j = 0; j < 4; ++j)                                        \
                part += fmaxf(acc2[mt][j], 0.0f) * wv[mt][j];                  \
        part += __shfl_xor(part, 16, 64);                                      \
        part += __shfl_xor(part, 32, 64);                                      \
        if (l < 16) {                                                          \
            int row = (TT) * 16 + cb;                                          \
            if (row < 200) out[(size_t)b * 200 + row] = part;                  \
        }                                                                      \
    } while (0)

    float4 sa0, sa1, sa2, sa3;
    float4 sb0, sb1, sb2, sb3;
    STAGE(0, sa0, sa1, sa2, sa3);
    #pragma unroll 1
    for (int i = 0; i < 6; ++i) {
        STAGE(2 * i + 1, sb0, sb1, sb2, sb3);
        PROC(2 * i,     sa0, sa1, sa2, sa3);
        STAGE(2 * i + 2, sa0, sa1, sa2, sa3);
        PROC(2 * i + 1, sb0, sb1, sb2, sb3);
    }
    PROC(12, sa0, sa1, sa2, sa3);
}

// ---------------- masked softmax, in place on d_out -------------------------
__global__ __launch_bounds__(256) void softmax_kernel(
    const int* __restrict__ mask, float* __restrict__ out)
{
    const int l = threadIdx.x & 63;
    const int w = threadIdx.x >> 6;
    const int b = blockIdx.x * 4 + w;             // grid 1024 -> 4096 batches
    float* po = out + (size_t)b * 200;
    const int* pm = mask + (size_t)b * 200;
    float v[4];
    #pragma unroll
    for (int j = 0; j < 4; ++j) {
        int tk = l + 64 * j;
        v[j] = (tk < 200) ? (pm[tk] ? po[tk] : -1.0e9f) : -3.0e38f;
    }
    float mx = fmaxf(fmaxf(v[0], v[1]), fmaxf(v[2], v[3]));
    #pragma unroll
    for (int st = 32; st >= 1; st >>= 1) mx = fmaxf(mx, __shfl_xor(mx, st, 64));
    float e[4], sm = 0.0f;
    #pragma unroll
    for (int j = 0; j < 4; ++j) {
        int tk = l + 64 * j;
        e[j] = (tk < 200) ? __expf(v[j] - mx) : 0.0f;
        sm += e[j];
    }
    #pragma unroll
    for (int st = 32; st >= 1; st >>= 1) sm += __shfl_xor(sm, st, 64);
    float inv = 1.0f / sm;
    #pragma unroll
    for (int j = 0; j < 4; ++j) {
        int tk = l + 64 * j;
        if (tk < 200) po[tk] = e[j] * inv;
    }
}

extern "C" void kernel_launch(void* const* d_in, const int* in_sizes, int n_in,
                              void* d_out, int out_size, void* d_ws, size_t ws_size,
                              hipStream_t stream)
{
    const float* seq = (const float*)d_in[0];
    const float* tgt = (const float*)d_in[1];
    const int*   msk = (const int*)d_in[2];
    const float* W1  = (const float*)d_in[3];
    const float* b1  = (const float*)d_in[4];
    const float* W2  = (const float*)d_in[5];
    const float* b2  = (const float*)d_in[6];
    const float* W3  = (const float*)d_in[7];
    // d_in[8] = b3: uniform shift, cancels in softmax.
    unsigned char* ws = (unsigned char*)d_ws;
    float* out = (float*)d_out;

    prep_w_kernel<<<1, 256, 0, stream>>>(W1, W2, b2, W3, ws);
    score_kernel<<<4096, 64, 0, stream>>>(seq, tgt, b1, ws, out);
    softmax_kernel<<<1024, 256, 0, stream>>>(msk, out);
}

// Round 12
// 80.709 us; speedup vs baseline: 1.6429x; 1.3605x over previous
//
#include <hip/hip_runtime.h>
#include <hip/hip_bf16.h>

// ---------------------------------------------------------------------------
// AttentionLayer: per-token MLP(256->80->40->1) + masked softmax.
// din@W1 = t@U + [s | t*s] @ [V;X].  Layer-1 TRANSPOSED (acc = mfma(W1,din),
// lane holds H1^T[chan=16nt+4kq+j][tok=cb]); layer-2 B-frags lane-local from
// acc vs sigma-permuted W2^T (sigma(kt,kq,e)=32kt+16*(e>=4)+4kq+(e&3)); bias
// in MFMA C-init.  Round-12: (1) v_cvt_pk_bf16_f32 replaces manual f2bf in
// the hot loop (~35% VALU cut: pk8 130->16 instr, H1 pack 80->10) [T12];
// (2) structure = measured-best R4/R6 shape: 512 blocks x 4 waves x 2
// batches/wave (26 tiles amortize setup), 256-thd blocks, (256,2), W1 in
// pre-swizzled LDS, separate softmax.  R5/R8: never (,4). R11: never 1-wave
// blocks.  Numerics: cvt_pk is HW RNE (same rounding as proven f2bf).
// ---------------------------------------------------------------------------

#define WS_WCT   0        // bf16 [80][128] PRE-SWIZZLED: u16 idx = c*128 + (k ^ ((c&7)<<3))
#define WS_W2T   20480    // bf16 [48][96]  sigma-permuted W2T (zero-padded)
#define WS_B2P   29696    // f32  [48]
#define WS_W3P   29888    // f32  [48]
#define WS_U     30080    // f32  [64][80]  U[d][h] = W1a+W1c   (ends at 50560)

typedef __attribute__((ext_vector_type(8))) short short8;
typedef __attribute__((ext_vector_type(4))) float f32x4;

static __device__ __forceinline__ unsigned short f2bf(float f) {
    unsigned int u = __builtin_bit_cast(unsigned int, f);
    u = (u + 0x7FFFu + ((u >> 16) & 1u)) >> 16;   // RNE, finite inputs (prep only)
    return (unsigned short)u;
}

// HW packed f32->bf16 (RNE), dst[15:0]=lo, dst[31:16]=hi  [T12, gfx950]
static __device__ __forceinline__ unsigned cvtpk(float lo, float hi) {
    unsigned r;
    asm("v_cvt_pk_bf16_f32 %0, %1, %2" : "=v"(r) : "v"(lo), "v"(hi));
    return r;
}

static __device__ __forceinline__ short8 pk8c(float4 a, float4 b) {
    union { unsigned u[4]; short8 s; } r;
    r.u[0] = cvtpk(a.x, a.y); r.u[1] = cvtpk(a.z, a.w);
    r.u[2] = cvtpk(b.x, b.y); r.u[3] = cvtpk(b.z, b.w);
    return r.s;
}

// ---------------- weight prep (1 block) ------------------------------------
__global__ __launch_bounds__(256) void prep_w_kernel(
    const float* __restrict__ W1, const float* __restrict__ W2,
    const float* __restrict__ b2, const float* __restrict__ W3,
    unsigned char* __restrict__ ws)
{
    const int tid = threadIdx.x;
    unsigned short* wcT = (unsigned short*)(ws + WS_WCT);
    for (int idx = tid; idx < 80 * 128; idx += 256) {
        int c = idx >> 7, k = idx & 127;
        float v;
        if (k < 64) v = W1[(64 + k) * 80 + c] - W1[(128 + k) * 80 + c]; // V
        else        v = W1[(192 + (k - 64)) * 80 + c];                  // X
        wcT[(c << 7) + (k ^ ((c & 7) << 3))] = f2bf(v);                 // swizzled
    }
    // sigma-permuted W2T: storage [c2][ks], ks=(kt,kq,e) -> real chan
    unsigned short* w2T = (unsigned short*)(ws + WS_W2T);
    for (int idx = tid; idx < 48 * 96; idx += 256) {
        int c2 = idx / 96, ks = idx - c2 * 96;
        int kt = ks >> 5, kq = (ks >> 3) & 3, e = ks & 7;
        int chan = 32 * kt + 16 * (e >> 2) + 4 * kq + (e & 3);
        float v = (c2 < 40 && chan < 80) ? W2[chan * 40 + c2] : 0.0f;
        w2T[idx] = f2bf(v);
    }
    float* b2p = (float*)(ws + WS_B2P);
    float* w3p = (float*)(ws + WS_W3P);
    for (int idx = tid; idx < 48; idx += 256) {
        b2p[idx] = (idx < 40) ? b2[idx] : 0.0f;
        w3p[idx] = (idx < 40) ? W3[idx] : 0.0f;
    }
    float* Uf = (float*)(ws + WS_U);
    for (int idx = tid; idx < 64 * 80; idx += 256) {
        int d = idx / 80, h = idx - d * 80;
        Uf[idx] = W1[d * 80 + h] + W1[(128 + d) * 80 + h];
    }
}

// ---------------- streaming score kernel ------------------------------------
__global__ __launch_bounds__(256, 2) void score_kernel(
    const float* __restrict__ seq, const float* __restrict__ tgt,
    const float* __restrict__ b1g, const unsigned char* __restrict__ ws,
    float* __restrict__ out)
{
    __shared__ __align__(16) unsigned char w1s[20480];      // pre-swizzled W1

    const int tid = threadIdx.x;
    {   // stage W1 (linear copy, pre-formatted in ws)
        const float4* s1 = (const float4*)(ws + WS_WCT);
        float4* d1 = (float4*)w1s;
        #pragma unroll
        for (int i = 0; i < 5; ++i) d1[tid + 256 * i] = s1[tid + 256 * i];
    }

    const int l  = tid & 63;
    const int w  = tid >> 6;
    const int cb = l & 15;
    const int kq = l >> 4;
    const int swi = (cb & 7) << 4;

    // W2Tp A-fragments + per-lane b2/w3 (c2 = 16mt + 4kq + j), from L2
    const unsigned short* w2T = (const unsigned short*)(ws + WS_W2T);
    short8 bL2[3][3];
    #pragma unroll
    for (int kt = 0; kt < 3; ++kt)
        #pragma unroll
        for (int mt = 0; mt < 3; ++mt)
            bL2[kt][mt] = *(const short8*)(w2T + (cb + 16 * mt) * 96 + kt * 32 + kq * 8);
    const float* b2p = (const float*)(ws + WS_B2P);
    const float* w3p = (const float*)(ws + WS_W3P);
    float bw[3][4], wv[3][4];
    #pragma unroll
    for (int mt = 0; mt < 3; ++mt)
        #pragma unroll
        for (int j = 0; j < 4; ++j) {
            int c2 = mt * 16 + kq * 4 + j;
            bw[mt][j] = b2p[c2]; wv[mt][j] = w3p[c2];
        }
    __syncthreads();   // w1s ready

    const int gw = blockIdx.x * 4 + w;            // 0..2047; 2 batches each

#define STAGE(TT, S0,S1,S2,S3) do {                                            \
        int row = (TT) * 16 + cb; row = row > 199 ? 199 : row;                 \
        const float* sp = seq + ((size_t)b * 200 + row) * 64 + kq * 8;         \
        S0 = *(const float4*)sp;        S1 = *(const float4*)(sp + 4);         \
        S2 = *(const float4*)(sp + 32); S3 = *(const float4*)(sp + 36);        \
    } while (0)

#define PROC(TT, S0,S1,S2,S3) do {                                            \
        short8 a0 = pk8c(S0, S1), a1 = pk8c(S2, S3);                           \
        short8 a2 = pk8c(T0 * S0, T1 * S1), a3 = pk8c(T2 * S2, T3 * S3);       \
        f32x4 acc[5];                                                          \
        _Pragma("unroll")                                                      \
        for (int nt = 0; nt < 5; ++nt) {                                       \
            acc[nt][0] = biasN[nt][0]; acc[nt][1] = biasN[nt][1];              \
            acc[nt][2] = biasN[nt][2]; acc[nt][3] = biasN[nt][3];              \
        }                                                                      \
        _Pragma("unroll")                                                      \
        for (int kt = 0; kt < 4; ++kt) {                                       \
            short8 av = kt == 0 ? a0 : kt == 1 ? a1 : kt == 2 ? a2 : a3;       \
            _Pragma("unroll")                                                  \
            for (int nt = 0; nt < 5; ++nt) {                                   \
                short8 bf = *(const short8*)(w1s + (cb + 16 * nt) * 256 +      \
                                             ((kt * 64 + kq * 16) ^ swi));     \
                acc[nt] = __builtin_amdgcn_mfma_f32_16x16x32_bf16(bf, av, acc[nt], 0, 0, 0); \
            }                                                                  \
        }                                                                      \
        uint2 p[5];                                                            \
        _Pragma("unroll")                                                      \
        for (int nt = 0; nt < 5; ++nt) {                                       \
            float h0 = fmaxf(acc[nt][0], 0.0f), h1 = fmaxf(acc[nt][1], 0.0f);  \
            float h2 = fmaxf(acc[nt][2], 0.0f), h3 = fmaxf(acc[nt][3], 0.0f);  \
            p[nt].x = cvtpk(h0, h1);                                           \
            p[nt].y = cvtpk(h2, h3);                                           \
        }                                                                      \
        f32x4 acc2[3];                                                         \
        _Pragma("unroll")                                                      \
        for (int mt = 0; mt < 3; ++mt) {                                       \
            acc2[mt][0] = bw[mt][0]; acc2[mt][1] = bw[mt][1];                  \
            acc2[mt][2] = bw[mt][2]; acc2[mt][3] = bw[mt][3];                  \
        }                                                                      \
        _Pragma("unroll")                                                      \
        for (int kt = 0; kt < 3; ++kt) {                                       \
            uint4 bb;                                                          \
            bb.x = p[2 * kt].x; bb.y = p[2 * kt].y;                            \
            bb.z = (kt < 2) ? p[2 * kt + 1].x : 0u;                            \
            bb.w = (kt < 2) ? p[2 * kt + 1].y : 0u;                            \
            short8 b2f = __builtin_bit_cast(short8, bb);                       \
            _Pragma("unroll")                                                  \
            for (int mt = 0; mt < 3; ++mt)                                     \
                acc2[mt] = __builtin_amdgcn_mfma_f32_16x16x32_bf16(bL2[kt][mt], b2f, acc2[mt], 0, 0, 0); \
        }                                                                      \
        float part = 0.0f;                                                     \
        _Pragma("unroll")                                                      \
        for (int mt = 0; mt < 3; ++mt)                                         \
            _Pragma("unroll")                                                  \
            for (int j = 0; j < 4; ++j)                                        \
                part += fmaxf(acc2[mt][j], 0.0f) * wv[mt][j];                  \
        part += __shfl_xor(part, 16, 64);                                      \
        part += __shfl_xor(part, 32, 64);                                      \
        if (l < 16) {                                                          \
            int row = (TT) * 16 + cb;                                          \
            if (row < 200) out[(size_t)b * 200 + row] = part;                  \
        }                                                                      \
    } while (0)

    #pragma unroll 1
    for (int bi = 0; bi < 2; ++bi) {
        const int b = gw * 2 + bi;

        // target fragments (constant per batch)
        const float* tp = tgt + (size_t)b * 64 + kq * 8;
        const float4 T0 = *(const float4*)tp;        const float4 T1 = *(const float4*)(tp + 4);
        const float4 T2 = *(const float4*)(tp + 32); const float4 T3 = *(const float4*)(tp + 36);

        // biasOld[nt] = b1[16nt+cb] + t@U[:,16nt+cb]  (f32, from L2)
        float biasOld[5];
        #pragma unroll
        for (int nt = 0; nt < 5; ++nt) biasOld[nt] = b1g[nt * 16 + cb];
        {
            const float* Uf = (const float*)(ws + WS_U);
            const float* tb = tgt + (size_t)b * 64;
            #pragma unroll 4
            for (int d = 0; d < 64; ++d) {
                float tA = tb[d];
                #pragma unroll
                for (int nt = 0; nt < 5; ++nt)
                    biasOld[nt] += tA * Uf[d * 80 + nt * 16 + cb];
            }
        }
        // redistribute to C-row indexing: biasN[nt][j] = bias[chan=16nt+4kq+j]
        float biasN[5][4];
        #pragma unroll
        for (int nt = 0; nt < 5; ++nt)
            #pragma unroll
            for (int j = 0; j < 4; ++j)
                biasN[nt][j] = __shfl(biasOld[nt], ((l >> 4) << 2) + j, 64);

        float4 sa0, sa1, sa2, sa3;
        float4 sb0, sb1, sb2, sb3;
        STAGE(0, sa0, sa1, sa2, sa3);
        #pragma unroll 1
        for (int i = 0; i < 6; ++i) {
            STAGE(2 * i + 1, sb0, sb1, sb2, sb3);
            PROC(2 * i,     sa0, sa1, sa2, sa3);
            STAGE(2 * i + 2, sa0, sa1, sa2, sa3);
            PROC(2 * i + 1, sb0, sb1, sb2, sb3);
        }
        PROC(12, sa0, sa1, sa2, sa3);
    }
}

// ---------------- masked softmax, in place on d_out -------------------------
__global__ __launch_bounds__(256) void softmax_kernel(
    const int* __restrict__ mask, float* __restrict__ out)
{
    const int l = threadIdx.x & 63;
    const int w = threadIdx.x >> 6;
    const int b = blockIdx.x * 4 + w;             // grid 1024 -> 4096 batches
    float* po = out + (size_t)b * 200;
    const int* pm = mask + (size_t)b * 200;
    float v[4];
    #pragma unroll
    for (int j = 0; j < 4; ++j) {
        int tk = l + 64 * j;
        v[j] = (tk < 200) ? (pm[tk] ? po[tk] : -1.0e9f) : -3.0e38f;
    }
    float mx = fmaxf(fmaxf(v[0], v[1]), fmaxf(v[2], v[3]));
    #pragma unroll
    for (int st = 32; st >= 1; st >>= 1) mx = fmaxf(mx, __shfl_xor(mx, st, 64));
    float e[4], sm = 0.0f;
    #pragma unroll
    for (int j = 0; j < 4; ++j) {
        int tk = l + 64 * j;
        e[j] = (tk < 200) ? __expf(v[j] - mx) : 0.0f;
        sm += e[j];
    }
    #pragma unroll
    for (int st = 32; st >= 1; st >>= 1) sm += __shfl_xor(sm, st, 64);
    float inv = 1.0f / sm;
    #pragma unroll
    for (int j = 0; j < 4; ++j) {
        int tk = l + 64 * j;
        if (tk < 200) po[tk] = e[j] * inv;
    }
}

extern "C" void kernel_launch(void* const* d_in, const int* in_sizes, int n_in,
                              void* d_out, int out_size, void* d_ws, size_t ws_size,
                              hipStream_t stream)
{
    const float* seq = (const float*)d_in[0];
    const float* tgt = (const float*)d_in[1];
    const int*   msk = (const int*)d_in[2];
    const float* W1  = (const float*)d_in[3];
    const float* b1  = (const float*)d_in[4];
    const float* W2  = (const float*)d_in[5];
    const float* b2  = (const float*)d_in[6];
    const float* W3  = (const float*)d_in[7];
    // d_in[8] = b3: uniform shift, cancels in softmax.
    unsigned char* ws = (unsigned char*)d_ws;
    float* out = (float*)d_out;

    prep_w_kernel<<<1, 256, 0, stream>>>(W1, W2, b2, W3, ws);
    score_kernel<<<512, 256, 0, stream>>>(seq, tgt, b1, ws, out);
    softmax_kernel<<<1024, 256, 0, stream>>>(msk, out);
}